// Round 4
// baseline (981.805 us; speedup 1.0000x reference)
//
#include <hip/hip_runtime.h>

// WKV7 recurrence, T=4096, H=32, N=64, fp32. One wave per state row.
// R3 post-mortem: VALU-issue-bound (~83 insts/step/wave). R4: kill address
// VALU via buffer loads (SGPR soffset, scalar pipe) and make DPP reduction
// fusable into v_add_f32_dpp (bound_ctrl=1 shift stages).

static constexpr int T_LEN = 4096;
static constexpr int H_HEADS = 32;
static constexpr int N_DIM = 64;
static constexpr int HN = H_HEADS * N_DIM;                 // 2048
static constexpr int WAVES_PER_BLOCK = 8;
static constexpr int BLOCK_THREADS = WAVES_PER_BLOCK * 64; // 512
static constexpr int NUM_BLOCKS = (H_HEADS * N_DIM) / WAVES_PER_BLOCK; // 256
static constexpr int C = 8;                                // chunk (steps)
static constexpr int TC = T_LEN / C;                       // 512 chunks

// ---- raw buffer load (CK-style): soffset rides the SGPR field -> 0 VALU ----
typedef int int32x4_t __attribute__((ext_vector_type(4)));
__device__ float llvm_amdgcn_raw_buffer_load_fp32(int32x4_t srsrc, int voffset,
                                                  int soffset, int glc_slc)
    __asm("llvm.amdgcn.raw.buffer.load.f32");

__device__ __forceinline__ int32x4_t make_srd(const void* p, unsigned bytes) {
  int32x4_t r;
  r.x = (int)(unsigned long long)p;
  r.y = (int)((unsigned long long)p >> 32); // stride=0 -> raw, num_records=bytes
  r.z = (int)bytes;
  r.w = 0x00020000; // raw dword access
  return r;
}

// ---- DPP reduction, fusion-friendly ----
// shift stages: bound_ctrl=1 (invalid lanes read 0, old dead -> fusable)
template <int CTRL>
__device__ __forceinline__ float dpp_add_bc(float x) {
  int m = __builtin_amdgcn_update_dpp(0, __float_as_int(x), CTRL, 0xf, 0xf, true);
  return x + __int_as_float(m);
}
// bcast stages: write-masked, old=0 == identity of add (in-place fusable)
template <int CTRL, int RM>
__device__ __forceinline__ float dpp_add_m(float x) {
  int m = __builtin_amdgcn_update_dpp(0, __float_as_int(x), CTRL, RM, 0xf, false);
  return x + __int_as_float(m);
}

// 64-lane sum; result broadcast via readlane(63)
__device__ __forceinline__ float wave_sum_bcast(float x) {
  x = dpp_add_bc<0x111>(x);       // row_shr:1
  x = dpp_add_bc<0x112>(x);       // row_shr:2
  x = dpp_add_bc<0x114>(x);       // row_shr:4
  x = dpp_add_bc<0x118>(x);       // row_shr:8
  x = dpp_add_m<0x142, 0xa>(x);   // row_bcast:15 -> rows 1,3
  x = dpp_add_m<0x143, 0xc>(x);   // row_bcast:31 -> rows 2,3
  return __int_as_float(__builtin_amdgcn_readlane(__float_as_int(x), 63));
}

__global__ __launch_bounds__(BLOCK_THREADS, 2) void wkv7_scan(
    const float* __restrict__ rp, const float* __restrict__ wp,
    const float* __restrict__ kp, const float* __restrict__ vp,
    const float* __restrict__ ap, const float* __restrict__ bp,
    const float* __restrict__ s0p, float* __restrict__ xp,
    float* __restrict__ sop) {
  const int tid  = threadIdx.x;
  const int lane = tid & 63;
  const int wv   = tid >> 6;
  const int blk  = blockIdx.x;
  const int h     = blk & (H_HEADS - 1);
  const int ibase = (blk >> 5) * WAVES_PER_BLOCK;
  const int i     = ibase + wv;
  const int hb    = h * N_DIM;

  __shared__ float xbuf[WAVES_PER_BLOCK][65];

  constexpr unsigned ARR_BYTES = (unsigned)T_LEN * HN * 4u;
  const int32x4_t srd_r = make_srd(rp, ARR_BYTES);
  const int32x4_t srd_w = make_srd(wp, ARR_BYTES);
  const int32x4_t srd_k = make_srd(kp, ARR_BYTES);
  const int32x4_t srd_a = make_srd(ap, ARR_BYTES);
  const int32x4_t srd_b = make_srd(bp, ARR_BYTES);

  float s = s0p[(size_t)(hb + i) * N_DIM + lane];

  const int vo4 = lane << 2;                                  // voffset (bytes)
  const int sbase = hb << 2;                                  // head byte offset
  const int vubase = __builtin_amdgcn_readfirstlane(hb + i);  // uniform v index

  float wb[2][C], ab_[2][C], bb[2][C], kb[2][C], rb[2][C], vb[2][C];
  float xacc = 0.0f;

  // soffset is wave-uniform -> SGPR field of buffer_load; OOB (past num_records)
  // reads return 0, so prefetch past the end needs no clamp. v (uniform s_load)
  // is clamped to stay in bounds.
#define LOAD_CHUNK(CI, BI)                                               \
  do {                                                                   \
    const int cb = (CI) * (C * HN);                                      \
    const int cc = ((CI) < TC - 1 ? (CI) : TC - 1) * (C * HN);           \
    _Pragma("unroll")                                                    \
    for (int u = 0; u < C; ++u) {                                        \
      const int so = ((cb + u * HN) << 2) + sbase;                       \
      wb[BI][u]  = llvm_amdgcn_raw_buffer_load_fp32(srd_w, vo4, so, 0);  \
      ab_[BI][u] = llvm_amdgcn_raw_buffer_load_fp32(srd_a, vo4, so, 0);  \
      bb[BI][u]  = llvm_amdgcn_raw_buffer_load_fp32(srd_b, vo4, so, 0);  \
      kb[BI][u]  = llvm_amdgcn_raw_buffer_load_fp32(srd_k, vo4, so, 0);  \
      rb[BI][u]  = llvm_amdgcn_raw_buffer_load_fp32(srd_r, vo4, so, 0);  \
      vb[BI][u]  = vp[cc + u * HN + vubase];                             \
    }                                                                    \
  } while (0)

#define COMPUTE_CHUNK(CI, BI)                                               \
  do {                                                                      \
    _Pragma("unroll")                                                       \
    for (int u = 0; u < C; ++u) {                                           \
      const float sa = wave_sum_bcast(s * ab_[BI][u]);                      \
      s = fmaf(s, wb[BI][u], fmaf(sa, bb[BI][u], vb[BI][u] * kb[BI][u]));   \
      const float xv = wave_sum_bcast(s * rb[BI][u]);                       \
      const int tl = (((CI) & 7) << 3) | u;                                 \
      xacc = (lane == tl) ? xv : xacc;                                      \
    }                                                                       \
  } while (0)

  LOAD_CHUNK(0, 0);

  for (int c = 0; c < TC; c += 2) {
    LOAD_CHUNK(c + 1, 1);
    COMPUTE_CHUNK(c, 0);
    LOAD_CHUNK(c + 2, 0);
    COMPUTE_CHUNK(c + 1, 1);

    if ((c & 7) == 6) {
      xbuf[wv][lane] = xacc;
      __syncthreads();
      const int tl2 = tid >> 3;
      const int iw  = tid & 7;
      const int t0  = (c + 2) * C - 64;
      xp[(size_t)(t0 + tl2) * HN + hb + ibase + iw] = xbuf[iw][tl2];
      __syncthreads();
    }
  }

#undef LOAD_CHUNK
#undef COMPUTE_CHUNK

  sop[(size_t)(hb + i) * N_DIM + lane] = s;
}

extern "C" void kernel_launch(void* const* d_in, const int* in_sizes, int n_in,
                              void* d_out, int out_size, void* d_ws, size_t ws_size,
                              hipStream_t stream) {
  // setup_inputs order: seq_length(int,1), r, w, k, v, a, b, state2
  const float* r  = (const float*)d_in[1];
  const float* w  = (const float*)d_in[2];
  const float* k  = (const float*)d_in[3];
  const float* v  = (const float*)d_in[4];
  const float* a  = (const float*)d_in[5];
  const float* b  = (const float*)d_in[6];
  const float* s0 = (const float*)d_in[7];
  float* x    = (float*)d_out;                       // [T,H,1,N] flat
  float* sout = x + (size_t)T_LEN * H_HEADS * N_DIM; // [H,N,N]

  wkv7_scan<<<dim3(NUM_BLOCKS), dim3(BLOCK_THREADS), 0, stream>>>(
      r, w, k, v, a, b, s0, x, sout);
}

// Round 5
// 872.960 us; speedup vs baseline: 1.1247x; 1.1247x over previous
//
#include <hip/hip_runtime.h>

// WKV7 recurrence, T=4096, H=32, N=64, fp32. One wave per state row.
// R4 post-mortem: buffer-load form let the scheduler sink loads next to uses
// (VGPR 96->40), collapsing the software pipeline. R5: identical body, plus
// sched_barrier(0) phase fences pinning LOAD_CHUNK before COMPUTE_CHUNK.

static constexpr int T_LEN = 4096;
static constexpr int H_HEADS = 32;
static constexpr int N_DIM = 64;
static constexpr int HN = H_HEADS * N_DIM;                 // 2048
static constexpr int WAVES_PER_BLOCK = 8;
static constexpr int BLOCK_THREADS = WAVES_PER_BLOCK * 64; // 512
static constexpr int NUM_BLOCKS = (H_HEADS * N_DIM) / WAVES_PER_BLOCK; // 256
static constexpr int C = 8;                                // chunk (steps)
static constexpr int TC = T_LEN / C;                       // 512 chunks

// ---- raw buffer load: soffset rides the SGPR field -> 0 VALU addr math ----
typedef int int32x4_t __attribute__((ext_vector_type(4)));
__device__ float llvm_amdgcn_raw_buffer_load_fp32(int32x4_t srsrc, int voffset,
                                                  int soffset, int glc_slc)
    __asm("llvm.amdgcn.raw.buffer.load.f32");

__device__ __forceinline__ int32x4_t make_srd(const void* p, unsigned bytes) {
  int32x4_t r;
  r.x = (int)(unsigned long long)p;
  r.y = (int)((unsigned long long)p >> 32); // stride=0 -> raw
  r.z = (int)bytes;                         // num_records: OOB loads return 0
  r.w = 0x00020000;                         // raw dword access
  return r;
}

// ---- DPP reduction, fusion-friendly ----
template <int CTRL>
__device__ __forceinline__ float dpp_add_bc(float x) { // bound_ctrl=1 -> fusable
  int m = __builtin_amdgcn_update_dpp(0, __float_as_int(x), CTRL, 0xf, 0xf, true);
  return x + __int_as_float(m);
}
template <int CTRL, int RM>
__device__ __forceinline__ float dpp_add_m(float x) { // masked rows, old=0
  int m = __builtin_amdgcn_update_dpp(0, __float_as_int(x), CTRL, RM, 0xf, false);
  return x + __int_as_float(m);
}

// 64-lane sum; result broadcast via readlane(63)
__device__ __forceinline__ float wave_sum_bcast(float x) {
  x = dpp_add_bc<0x111>(x);     // row_shr:1
  x = dpp_add_bc<0x112>(x);     // row_shr:2
  x = dpp_add_bc<0x114>(x);     // row_shr:4
  x = dpp_add_bc<0x118>(x);     // row_shr:8
  x = dpp_add_m<0x142, 0xa>(x); // row_bcast:15 -> rows 1,3
  x = dpp_add_m<0x143, 0xc>(x); // row_bcast:31 -> rows 2,3
  return __int_as_float(__builtin_amdgcn_readlane(__float_as_int(x), 63));
}

__global__ __launch_bounds__(BLOCK_THREADS, 2) void wkv7_scan(
    const float* __restrict__ rp, const float* __restrict__ wp,
    const float* __restrict__ kp, const float* __restrict__ vp,
    const float* __restrict__ ap, const float* __restrict__ bp,
    const float* __restrict__ s0p, float* __restrict__ xp,
    float* __restrict__ sop) {
  const int tid  = threadIdx.x;
  const int lane = tid & 63;
  const int wv   = tid >> 6;
  const int blk  = blockIdx.x;
  const int h     = blk & (H_HEADS - 1);
  const int ibase = (blk >> 5) * WAVES_PER_BLOCK;
  const int i     = ibase + wv;
  const int hb    = h * N_DIM;

  __shared__ float xbuf[WAVES_PER_BLOCK][65];

  constexpr unsigned ARR_BYTES = (unsigned)T_LEN * HN * 4u;
  const int32x4_t srd_r = make_srd(rp, ARR_BYTES);
  const int32x4_t srd_w = make_srd(wp, ARR_BYTES);
  const int32x4_t srd_k = make_srd(kp, ARR_BYTES);
  const int32x4_t srd_a = make_srd(ap, ARR_BYTES);
  const int32x4_t srd_b = make_srd(bp, ARR_BYTES);

  float s = s0p[(size_t)(hb + i) * N_DIM + lane];

  const int vo4 = lane << 2;                                  // voffset (bytes)
  const int sbase = hb << 2;                                  // head byte offset
  const int vubase = __builtin_amdgcn_readfirstlane(hb + i);  // uniform v index

  float wb[2][C], ab_[2][C], bb[2][C], kb[2][C], rb[2][C], vb[2][C];
  float xacc = 0.0f;

#define LOAD_CHUNK(CI, BI)                                               \
  do {                                                                   \
    const int cb = (CI) * (C * HN);                                      \
    const int cc = ((CI) < TC - 1 ? (CI) : TC - 1) * (C * HN);           \
    _Pragma("unroll")                                                    \
    for (int u = 0; u < C; ++u) {                                        \
      const int so = ((cb + u * HN) << 2) + sbase;                       \
      wb[BI][u]  = llvm_amdgcn_raw_buffer_load_fp32(srd_w, vo4, so, 0);  \
      ab_[BI][u] = llvm_amdgcn_raw_buffer_load_fp32(srd_a, vo4, so, 0);  \
      bb[BI][u]  = llvm_amdgcn_raw_buffer_load_fp32(srd_b, vo4, so, 0);  \
      kb[BI][u]  = llvm_amdgcn_raw_buffer_load_fp32(srd_k, vo4, so, 0);  \
      rb[BI][u]  = llvm_amdgcn_raw_buffer_load_fp32(srd_r, vo4, so, 0);  \
      vb[BI][u]  = vp[cc + u * HN + vubase];                             \
    }                                                                    \
  } while (0)

#define COMPUTE_CHUNK(CI, BI)                                               \
  do {                                                                      \
    _Pragma("unroll")                                                       \
    for (int u = 0; u < C; ++u) {                                           \
      const float sa = wave_sum_bcast(s * ab_[BI][u]);                      \
      s = fmaf(s, wb[BI][u], fmaf(sa, bb[BI][u], vb[BI][u] * kb[BI][u]));   \
      const float xv = wave_sum_bcast(s * rb[BI][u]);                       \
      const int tl = (((CI) & 7) << 3) | u;                                 \
      xacc = (lane == tl) ? xv : xacc;                                      \
    }                                                                       \
  } while (0)

  LOAD_CHUNK(0, 0);

  for (int c = 0; c < TC; c += 2) {
    // Phase fences: scheduler free WITHIN each phase, but loads of chunk c+1
    // cannot sink into compute of chunk c (R4's pipeline collapse).
    __builtin_amdgcn_sched_barrier(0);
    LOAD_CHUNK(c + 1, 1);
    __builtin_amdgcn_sched_barrier(0);
    COMPUTE_CHUNK(c, 0);
    __builtin_amdgcn_sched_barrier(0);
    LOAD_CHUNK(c + 2, 0);
    __builtin_amdgcn_sched_barrier(0);
    COMPUTE_CHUNK(c + 1, 1);
    __builtin_amdgcn_sched_barrier(0);

    if ((c & 7) == 6) {
      xbuf[wv][lane] = xacc;
      __syncthreads();
      const int tl2 = tid >> 3;
      const int iw  = tid & 7;
      const int t0  = (c + 2) * C - 64;
      xp[(size_t)(t0 + tl2) * HN + hb + ibase + iw] = xbuf[iw][tl2];
      __syncthreads();
    }
  }

#undef LOAD_CHUNK
#undef COMPUTE_CHUNK

  sop[(size_t)(hb + i) * N_DIM + lane] = s;
}

extern "C" void kernel_launch(void* const* d_in, const int* in_sizes, int n_in,
                              void* d_out, int out_size, void* d_ws, size_t ws_size,
                              hipStream_t stream) {
  // setup_inputs order: seq_length(int,1), r, w, k, v, a, b, state2
  const float* r  = (const float*)d_in[1];
  const float* w  = (const float*)d_in[2];
  const float* k  = (const float*)d_in[3];
  const float* v  = (const float*)d_in[4];
  const float* a  = (const float*)d_in[5];
  const float* b  = (const float*)d_in[6];
  const float* s0 = (const float*)d_in[7];
  float* x    = (float*)d_out;                       // [T,H,1,N] flat
  float* sout = x + (size_t)T_LEN * H_HEADS * N_DIM; // [H,N,N]

  wkv7_scan<<<dim3(NUM_BLOCKS), dim3(BLOCK_THREADS), 0, stream>>>(
      r, w, k, v, a, b, s0, x, sout);
}

// Round 6
// 815.229 us; speedup vs baseline: 1.2043x; 1.0708x over previous
//
#include <hip/hip_runtime.h>

// WKV7 recurrence, T=4096, H=32, N=64, fp32. One wave per state row.
// R5 post-mortem: register double-buffer keeps collapsing (VGPR 52) — the
// compiler won't hold 96 load results live. R6: pipeline through LDS instead.
// Per 16-step chunk: issue block-cooperative staging loads (dedupes the 8x
// redundant head-vector reads), compute current chunk from LDS, then
// ds_write the staged regs and __syncthreads (vmcnt wait lands AFTER compute).

static constexpr int T_LEN = 4096;
static constexpr int H_HEADS = 32;
static constexpr int N_DIM = 64;
static constexpr int HN = H_HEADS * N_DIM;                 // 2048
static constexpr int WPB = 8;                              // waves/block
static constexpr int BT = WPB * 64;                        // 512 threads
static constexpr int NB = (H_HEADS * N_DIM) / WPB;         // 256 blocks
static constexpr int C = 16;                               // steps/chunk
static constexpr int TC = T_LEN / C;                       // 256 chunks

// ---- raw buffer load: SGPR soffset, OOB-safe prefetch (returns 0) ----
typedef int int32x4_t __attribute__((ext_vector_type(4)));
__device__ float llvm_amdgcn_raw_buffer_load_fp32(int32x4_t srsrc, int voffset,
                                                  int soffset, int glc_slc)
    __asm("llvm.amdgcn.raw.buffer.load.f32");

__device__ __forceinline__ int32x4_t make_srd(const void* p, unsigned bytes) {
  int32x4_t r;
  r.x = (int)(unsigned long long)p;
  r.y = (int)((unsigned long long)p >> 32); // stride=0 -> raw
  r.z = (int)bytes;                         // num_records
  r.w = 0x00020000;                         // raw dword
  return r;
}

// ---- DPP 64-lane sum, fusion-friendly ----
template <int CTRL>
__device__ __forceinline__ float dpp_add_bc(float x) {
  int m = __builtin_amdgcn_update_dpp(0, __float_as_int(x), CTRL, 0xf, 0xf, true);
  return x + __int_as_float(m);
}
template <int CTRL, int RM>
__device__ __forceinline__ float dpp_add_m(float x) {
  int m = __builtin_amdgcn_update_dpp(0, __float_as_int(x), CTRL, RM, 0xf, false);
  return x + __int_as_float(m);
}
__device__ __forceinline__ float wave_sum_bcast(float x) {
  x = dpp_add_bc<0x111>(x);     // row_shr:1
  x = dpp_add_bc<0x112>(x);     // row_shr:2
  x = dpp_add_bc<0x114>(x);     // row_shr:4
  x = dpp_add_bc<0x118>(x);     // row_shr:8
  x = dpp_add_m<0x142, 0xa>(x); // row_bcast:15
  x = dpp_add_m<0x143, 0xc>(x); // row_bcast:31
  return __int_as_float(__builtin_amdgcn_readlane(__float_as_int(x), 63));
}

__global__ __launch_bounds__(BT, 2) void wkv7_scan(
    const float* __restrict__ rp, const float* __restrict__ wp,
    const float* __restrict__ kp, const float* __restrict__ vp,
    const float* __restrict__ ap, const float* __restrict__ bp,
    const float* __restrict__ s0p, float* __restrict__ xp,
    float* __restrict__ sop) {
  const int tid  = threadIdx.x;
  const int lane = tid & 63;
  const int wv   = tid >> 6;
  const int blk  = blockIdx.x;
  const int h     = blk & (H_HEADS - 1);
  const int ibase = (blk >> 5) * WPB;
  const int i     = ibase + wv;
  const int hb    = h * N_DIM;

  // [buf][step][channel]: read addr = lane*4 + const -> 2-way (free)
  __shared__ float sw[2][C][N_DIM], sA[2][C][N_DIM], sB[2][C][N_DIM],
                   sK[2][C][N_DIM], sR[2][C][N_DIM];
  __shared__ float sV[2][C][WPB];
  __shared__ float xbuf[WPB][65];

  constexpr unsigned ARR_BYTES = (unsigned)T_LEN * HN * 4u;
  const int32x4_t srd_r = make_srd(rp, ARR_BYTES);
  const int32x4_t srd_w = make_srd(wp, ARR_BYTES);
  const int32x4_t srd_k = make_srd(kp, ARR_BYTES);
  const int32x4_t srd_v = make_srd(vp, ARR_BYTES);
  const int32x4_t srd_a = make_srd(ap, ARR_BYTES);
  const int32x4_t srd_b = make_srd(bp, ARR_BYTES);

  float s = s0p[(size_t)(hb + i) * N_DIM + lane];

  // staging index map: thread covers (u0, j) and (u0+8, j) for 5 arrays
  const int j   = lane;
  const int u0  = tid >> 6;                       // 0..7
  const int vo0 = (u0 * HN + j) << 2;             // pass 0 voffset (bytes)
  const int vo1 = vo0 + (8 * HN << 2);            // pass 1
  const int sbase = hb << 2;
  // v staging: waves 0-1 (tid<128): u=tid>>3 (0..15), q=tid&7
  const int uv  = tid >> 3;
  const int qv  = tid & 7;
  const int vov = (uv * HN + qv) << 2;
  const int svbase = (hb + ibase) << 2;

  float g0, g1, g2, g3, g4, g5, g6, g7, g8, g9, g10;

#define STAGE_LOAD(CI)                                                   \
  do {                                                                   \
    const int so = (CI) * (C * HN * 4) + sbase;                          \
    g0 = llvm_amdgcn_raw_buffer_load_fp32(srd_w, vo0, so, 0);            \
    g1 = llvm_amdgcn_raw_buffer_load_fp32(srd_a, vo0, so, 0);            \
    g2 = llvm_amdgcn_raw_buffer_load_fp32(srd_b, vo0, so, 0);            \
    g3 = llvm_amdgcn_raw_buffer_load_fp32(srd_k, vo0, so, 0);            \
    g4 = llvm_amdgcn_raw_buffer_load_fp32(srd_r, vo0, so, 0);            \
    g5 = llvm_amdgcn_raw_buffer_load_fp32(srd_w, vo1, so, 0);            \
    g6 = llvm_amdgcn_raw_buffer_load_fp32(srd_a, vo1, so, 0);            \
    g7 = llvm_amdgcn_raw_buffer_load_fp32(srd_b, vo1, so, 0);            \
    g8 = llvm_amdgcn_raw_buffer_load_fp32(srd_k, vo1, so, 0);            \
    g9 = llvm_amdgcn_raw_buffer_load_fp32(srd_r, vo1, so, 0);            \
    if (wv < 2)                                                          \
      g10 = llvm_amdgcn_raw_buffer_load_fp32(                            \
          srd_v, vov, (CI) * (C * HN * 4) + svbase, 0);                  \
  } while (0)

#define STAGE_STORE(BI)                                                  \
  do {                                                                   \
    sw[BI][u0][j] = g0;  sA[BI][u0][j] = g1;  sB[BI][u0][j] = g2;        \
    sK[BI][u0][j] = g3;  sR[BI][u0][j] = g4;                             \
    sw[BI][u0 + 8][j] = g5;  sA[BI][u0 + 8][j] = g6;                     \
    sB[BI][u0 + 8][j] = g7;  sK[BI][u0 + 8][j] = g8;                     \
    sR[BI][u0 + 8][j] = g9;                                              \
    if (wv < 2) sV[BI][uv][qv] = g10;                                    \
  } while (0)

  float xacc = 0.0f;

  STAGE_LOAD(0);
  STAGE_STORE(0);
  __syncthreads();

  for (int c = 0; c < TC; ++c) {
    const int bi = c & 1;

    STAGE_LOAD(c + 1);              // loads fly under compute
    __builtin_amdgcn_sched_barrier(0);

#pragma unroll
    for (int u = 0; u < C; ++u) {
      const float wc = sw[bi][u][lane];
      const float ac = sA[bi][u][lane];
      const float bc = sB[bi][u][lane];
      const float kc = sK[bi][u][lane];
      const float rc = sR[bi][u][lane];
      const float vc = sV[bi][u][wv];
      const float sa = wave_sum_bcast(s * ac);
      s = fmaf(s, wc, fmaf(sa, bc, vc * kc));
      const float xv = wave_sum_bcast(s * rc);
      const int tl = ((c & 3) << 4) | u;
      xacc = (lane == tl) ? xv : xacc;
    }

    __builtin_amdgcn_sched_barrier(0);
    STAGE_STORE(bi ^ 1);            // vmcnt wait lands here, after compute
    __syncthreads();

    if ((c & 3) == 3) {
      // 64 steps complete: transpose through LDS -> coalesced stores
      xbuf[wv][lane] = xacc;
      __syncthreads();
      const int tl2 = tid >> 3;
      const int iw  = tid & 7;
      const int t0  = (c + 1) * C - 64;
      xp[(size_t)(t0 + tl2) * HN + hb + ibase + iw] = xbuf[iw][tl2];
      // no extra barrier: next xbuf write is 4 chunk-barriers away
    }
  }

#undef STAGE_LOAD
#undef STAGE_STORE

  sop[(size_t)(hb + i) * N_DIM + lane] = s;
}

extern "C" void kernel_launch(void* const* d_in, const int* in_sizes, int n_in,
                              void* d_out, int out_size, void* d_ws, size_t ws_size,
                              hipStream_t stream) {
  // setup_inputs order: seq_length(int,1), r, w, k, v, a, b, state2
  const float* r  = (const float*)d_in[1];
  const float* w  = (const float*)d_in[2];
  const float* k  = (const float*)d_in[3];
  const float* v  = (const float*)d_in[4];
  const float* a  = (const float*)d_in[5];
  const float* b  = (const float*)d_in[6];
  const float* s0 = (const float*)d_in[7];
  float* x    = (float*)d_out;                       // [T,H,1,N] flat
  float* sout = x + (size_t)T_LEN * H_HEADS * N_DIM; // [H,N,N]

  wkv7_scan<<<dim3(NB), dim3(BT), 0, stream>>>(r, w, k, v, a, b, s0, x, sout);
}

// Round 7
// 772.934 us; speedup vs baseline: 1.2702x; 1.0547x over previous
//
#include <hip/hip_runtime.h>

// WKV7 recurrence, T=4096, H=32, N=64, fp32. One wave per state row.
// R6 post-mortem: ~68 inst/step/wave compiled vs ~22 ideal — DPP reduction
// stages not fusing (3 inst/stage) + per-step LDS stalls. R7: inline-asm
// fused v_add_f32_dpp reduction (6 VALU exactly, s_nop hazard guards) and
// one-step LDS prefetch inside the unrolled chunk loop.

static constexpr int T_LEN = 4096;
static constexpr int H_HEADS = 32;
static constexpr int N_DIM = 64;
static constexpr int HN = H_HEADS * N_DIM;                 // 2048
static constexpr int WPB = 8;                              // waves/block
static constexpr int BT = WPB * 64;                        // 512 threads
static constexpr int NB = (H_HEADS * N_DIM) / WPB;         // 256 blocks
static constexpr int C = 16;                               // steps/chunk
static constexpr int TC = T_LEN / C;                       // 256 chunks

// ---- raw buffer load: SGPR soffset, OOB-safe prefetch (returns 0) ----
typedef int int32x4_t __attribute__((ext_vector_type(4)));
__device__ float llvm_amdgcn_raw_buffer_load_fp32(int32x4_t srsrc, int voffset,
                                                  int soffset, int glc_slc)
    __asm("llvm.amdgcn.raw.buffer.load.f32");

__device__ __forceinline__ int32x4_t make_srd(const void* p, unsigned bytes) {
  int32x4_t r;
  r.x = (int)(unsigned long long)p;
  r.y = (int)((unsigned long long)p >> 32); // stride=0 -> raw
  r.z = (int)bytes;                         // num_records
  r.w = 0x00020000;                         // raw dword
  return r;
}

// ---- 64-lane sum, hand-encoded fused DPP (exactly 6 VALU) ----
// Canonical GCN sequence; s_nop 1 guards the "VALU writes VGPR -> DPP reads
// it as src" 2-wait-state hazard (software-enforced on gfx9 lineage).
__device__ __forceinline__ float wave_sum_bcast(float x) {
  asm volatile(
      "s_nop 1\n\t"
      "v_add_f32 %0, %0, %0 row_shr:1 bound_ctrl:0\n\t"
      "s_nop 1\n\t"
      "v_add_f32 %0, %0, %0 row_shr:2 bound_ctrl:0\n\t"
      "s_nop 1\n\t"
      "v_add_f32 %0, %0, %0 row_shr:4 bound_ctrl:0\n\t"
      "s_nop 1\n\t"
      "v_add_f32 %0, %0, %0 row_shr:8 bound_ctrl:0\n\t"
      "s_nop 1\n\t"
      "v_add_f32 %0, %0, %0 row_bcast:15 row_mask:0xa\n\t"
      "s_nop 1\n\t"
      "v_add_f32 %0, %0, %0 row_bcast:31 row_mask:0xc\n\t"
      "s_nop 1\n\t"
      : "+v"(x));
  return __int_as_float(__builtin_amdgcn_readlane(__float_as_int(x), 63));
}

__global__ __launch_bounds__(BT, 2) void wkv7_scan(
    const float* __restrict__ rp, const float* __restrict__ wp,
    const float* __restrict__ kp, const float* __restrict__ vp,
    const float* __restrict__ ap, const float* __restrict__ bp,
    const float* __restrict__ s0p, float* __restrict__ xp,
    float* __restrict__ sop) {
  const int tid  = threadIdx.x;
  const int lane = tid & 63;
  const int wv   = tid >> 6;
  const int blk  = blockIdx.x;
  const int h     = blk & (H_HEADS - 1);
  const int ibase = (blk >> 5) * WPB;
  const int i     = ibase + wv;
  const int hb    = h * N_DIM;

  // [buf][step][channel]: read addr = lane*4 + imm -> conflict-free
  __shared__ float sw[2][C][N_DIM], sA[2][C][N_DIM], sB[2][C][N_DIM],
                   sK[2][C][N_DIM], sR[2][C][N_DIM];
  __shared__ float sV[2][C][WPB];
  __shared__ float xbuf[WPB][65];

  constexpr unsigned ARR_BYTES = (unsigned)T_LEN * HN * 4u;
  const int32x4_t srd_r = make_srd(rp, ARR_BYTES);
  const int32x4_t srd_w = make_srd(wp, ARR_BYTES);
  const int32x4_t srd_k = make_srd(kp, ARR_BYTES);
  const int32x4_t srd_v = make_srd(vp, ARR_BYTES);
  const int32x4_t srd_a = make_srd(ap, ARR_BYTES);
  const int32x4_t srd_b = make_srd(bp, ARR_BYTES);

  float s = s0p[(size_t)(hb + i) * N_DIM + lane];

  // staging index map: thread covers (u0, j) and (u0+8, j) for 5 arrays
  const int j   = lane;
  const int u0  = tid >> 6;                       // 0..7
  const int vo0 = (u0 * HN + j) << 2;             // pass 0 voffset (bytes)
  const int vo1 = vo0 + (8 * HN << 2);            // pass 1
  const int sbase = hb << 2;
  // v staging: waves 0-1 (tid<128): u=tid>>3 (0..15), q=tid&7
  const int uv  = tid >> 3;
  const int qv  = tid & 7;
  const int vov = (uv * HN + qv) << 2;
  const int svbase = (hb + ibase) << 2;

  float g0, g1, g2, g3, g4, g5, g6, g7, g8, g9, g10;

#define STAGE_LOAD(CI)                                                   \
  do {                                                                   \
    const int so = (CI) * (C * HN * 4) + sbase;                          \
    g0 = llvm_amdgcn_raw_buffer_load_fp32(srd_w, vo0, so, 0);            \
    g1 = llvm_amdgcn_raw_buffer_load_fp32(srd_a, vo0, so, 0);            \
    g2 = llvm_amdgcn_raw_buffer_load_fp32(srd_b, vo0, so, 0);            \
    g3 = llvm_amdgcn_raw_buffer_load_fp32(srd_k, vo0, so, 0);            \
    g4 = llvm_amdgcn_raw_buffer_load_fp32(srd_r, vo0, so, 0);            \
    g5 = llvm_amdgcn_raw_buffer_load_fp32(srd_w, vo1, so, 0);            \
    g6 = llvm_amdgcn_raw_buffer_load_fp32(srd_a, vo1, so, 0);            \
    g7 = llvm_amdgcn_raw_buffer_load_fp32(srd_b, vo1, so, 0);            \
    g8 = llvm_amdgcn_raw_buffer_load_fp32(srd_k, vo1, so, 0);            \
    g9 = llvm_amdgcn_raw_buffer_load_fp32(srd_r, vo1, so, 0);            \
    if (wv < 2)                                                          \
      g10 = llvm_amdgcn_raw_buffer_load_fp32(                            \
          srd_v, vov, (CI) * (C * HN * 4) + svbase, 0);                  \
  } while (0)

#define STAGE_STORE(BI)                                                  \
  do {                                                                   \
    sw[BI][u0][j] = g0;  sA[BI][u0][j] = g1;  sB[BI][u0][j] = g2;        \
    sK[BI][u0][j] = g3;  sR[BI][u0][j] = g4;                             \
    sw[BI][u0 + 8][j] = g5;  sA[BI][u0 + 8][j] = g6;                     \
    sB[BI][u0 + 8][j] = g7;  sK[BI][u0 + 8][j] = g8;                     \
    sR[BI][u0 + 8][j] = g9;                                              \
    if (wv < 2) sV[BI][uv][qv] = g10;                                    \
  } while (0)

  float xacc = 0.0f;

  STAGE_LOAD(0);
  STAGE_STORE(0);
  __syncthreads();

  for (int c = 0; c < TC; ++c) {
    const int bi = c & 1;

    STAGE_LOAD(c + 1);              // global loads fly under compute
    __builtin_amdgcn_sched_barrier(0);

    // one-step LDS prefetch: step u+1's reads issue before step u's chains
    float lw = sw[bi][0][lane], la = sA[bi][0][lane], lb = sB[bi][0][lane],
          lk = sK[bi][0][lane], lr = sR[bi][0][lane], lv = sV[bi][0][wv];
#pragma unroll
    for (int u = 0; u < C; ++u) {
      const int un = (u < C - 1) ? u + 1 : u;  // compile-time per iter
      const float nw = sw[bi][un][lane], na = sA[bi][un][lane],
                  nb = sB[bi][un][lane], nk = sK[bi][un][lane],
                  nr = sR[bi][un][lane], nv = sV[bi][un][wv];

      const float sa = wave_sum_bcast(s * la);
      s = fmaf(s, lw, fmaf(sa, lb, lv * lk));
      const float xv = wave_sum_bcast(s * lr);
      const int tl = ((c & 3) << 4) | u;
      xacc = (lane == tl) ? xv : xacc;

      lw = nw; la = na; lb = nb; lk = nk; lr = nr; lv = nv;
    }

    __builtin_amdgcn_sched_barrier(0);
    STAGE_STORE(bi ^ 1);            // vmcnt wait lands here, after compute
    __syncthreads();

    if ((c & 3) == 3) {
      // 64 steps complete: transpose through LDS -> coalesced stores
      xbuf[wv][lane] = xacc;
      __syncthreads();
      const int tl2 = tid >> 3;
      const int iw  = tid & 7;
      const int t0  = (c + 1) * C - 64;
      xp[(size_t)(t0 + tl2) * HN + hb + ibase + iw] = xbuf[iw][tl2];
      // no trailing barrier needed: next xbuf write is 4 chunk-barriers away
    }
  }

#undef STAGE_LOAD
#undef STAGE_STORE

  sop[(size_t)(hb + i) * N_DIM + lane] = s;
}

extern "C" void kernel_launch(void* const* d_in, const int* in_sizes, int n_in,
                              void* d_out, int out_size, void* d_ws, size_t ws_size,
                              hipStream_t stream) {
  // setup_inputs order: seq_length(int,1), r, w, k, v, a, b, state2
  const float* r  = (const float*)d_in[1];
  const float* w  = (const float*)d_in[2];
  const float* k  = (const float*)d_in[3];
  const float* v  = (const float*)d_in[4];
  const float* a  = (const float*)d_in[5];
  const float* b  = (const float*)d_in[6];
  const float* s0 = (const float*)d_in[7];
  float* x    = (float*)d_out;                       // [T,H,1,N] flat
  float* sout = x + (size_t)T_LEN * H_HEADS * N_DIM; // [H,N,N]

  wkv7_scan<<<dim3(NB), dim3(BT), 0, stream>>>(r, w, k, v, a, b, s0, x, sout);
}